// Round 1
// baseline (1077.501 us; speedup 1.0000x reference)
//
#include <hip/hip_runtime.h>

#define N_NODES 100000
#define N_EDGES 1600000
#define NB      1024
#define C_INF   64
#define HIDF    32
#define TF      4
#define MIDF    128
#define OUTF    128
#define EPSF    1e-5f

// ---------------- segment-sum jet = segment_sum(x*w, ind, B) -------------
template<int C>
__global__ __launch_bounds__(256) void jet_kernel(const float* __restrict__ x,
                                                  const float* __restrict__ w,
                                                  const int* __restrict__ ind,
                                                  float* __restrict__ jet) {
    int tid = blockIdx.x * 256 + threadIdx.x;
    if (tid >= N_NODES * C) return;
    int n = tid / C;
    int c = tid % C;
    float v = x[tid] * w[n];
    atomicAdd(&jet[ind[n] * C + c], v);
}

// -------------- per-channel mean/var(ddof=1) -> scale/shift --------------
template<int C>
__global__ __launch_bounds__(256) void stats_kernel(const float* __restrict__ jet,
                                                    const float* __restrict__ g,
                                                    const float* __restrict__ b,
                                                    float* __restrict__ scale,
                                                    float* __restrict__ shift) {
    int c = blockIdx.x;           // one block per channel
    int t = threadIdx.x;
    float s = 0.f, s2 = 0.f;
    for (int r = t; r < NB; r += 256) {
        float v = jet[r * C + c];
        s += v; s2 += v * v;
    }
    __shared__ float ls[256], ls2[256];
    ls[t] = s; ls2[t] = s2;
    __syncthreads();
    for (int ofs = 128; ofs > 0; ofs >>= 1) {
        if (t < ofs) { ls[t] += ls[t + ofs]; ls2[t] += ls2[t + ofs]; }
        __syncthreads();
    }
    if (t == 0) {
        float mean = ls[0] / (float)NB;
        float var  = (ls2[0] - (float)NB * mean * mean) / (float)(NB - 1);
        float sc   = g[c] / sqrtf(var + EPSF);
        scale[c] = sc;
        shift[c] = b[c] - mean * sc;
    }
}

// --------- fused1: shortcut GEMM + bn1+relu + @W1^T * w  -----------------
// tile of 16 rows; 256 threads = 16 rows x 16 col-threads; 10 outputs each
#define TILE1 16
__global__ __launch_bounds__(256) void fused1_kernel(const float* __restrict__ x,
                                                     const float* __restrict__ w,
                                                     const float* __restrict__ scale,
                                                     const float* __restrict__ shift,
                                                     const float* __restrict__ Wsc,
                                                     const float* __restrict__ W1,
                                                     float* __restrict__ h_small,
                                                     float* __restrict__ out) {
    __shared__ __align__(16) float xs[TILE1][68];   // raw
    __shared__ __align__(16) float xn[TILE1][68];   // bn+relu
    __shared__ __align__(16) float Wl[160][68];     // 0..127 Wsc, 128..159 W1
    int tid = threadIdx.x;
    int n0  = blockIdx.x * TILE1;

    for (int i = tid; i < 128 * 64; i += 256) Wl[i >> 6][i & 63] = Wsc[i];
    for (int i = tid; i < 32 * 64;  i += 256) Wl[128 + (i >> 6)][i & 63] = W1[i];
    for (int i = tid; i < TILE1 * 64; i += 256) {
        int r = i >> 6, c = i & 63;
        int n = n0 + r;
        float v = (n < N_NODES) ? x[n * 64 + c] : 0.f;
        xs[r][c] = v;
        float vn = v * scale[c] + shift[c];
        xn[r][c] = vn > 0.f ? vn : 0.f;
    }
    __syncthreads();

    int r = tid >> 4;      // 0..15
    int s = tid & 15;      // 0..15
    float acc[10];
#pragma unroll
    for (int k = 0; k < 10; k++) acc[k] = 0.f;

    for (int c = 0; c < 64; c += 4) {
        float4 xr  = *(const float4*)&xs[r][c];
        float4 xnr = *(const float4*)&xn[r][c];
#pragma unroll
        for (int k = 0; k < 10; k++) {
            int row = (k < 8) ? (s + 16 * k) : (128 + s + 16 * (k - 8));
            float4 wv = *(const float4*)&Wl[row][c];
            float4 xv = (k < 8) ? xr : xnr;
            acc[k] += xv.x * wv.x + xv.y * wv.y + xv.z * wv.z + xv.w * wv.w;
        }
    }
    int n = n0 + r;
    if (n < N_NODES) {
        float ww = w[n];
#pragma unroll
        for (int k = 0; k < 8; k++) out[n * 128 + s + 16 * k] = acc[k];
#pragma unroll
        for (int k = 8; k < 10; k++) h_small[n * 32 + s + 16 * (k - 8)] = acc[k] * ww;
    }
}

// -------------- edge scatter: agg[head] += h_small[tail] (x) pf ----------
__global__ __launch_bounds__(256) void edge_kernel(const int* __restrict__ head,
                                                   const int* __restrict__ tail,
                                                   const float* __restrict__ pf,
                                                   const float* __restrict__ h_small,
                                                   float* __restrict__ agg) {
    int tid = blockIdx.x * 256 + threadIdx.x;
    if (tid >= N_EDGES * 128) return;
    int e = tid >> 7;
    int j = tid & 127;          // j = i*4 + t
    int i = j >> 2, t = j & 3;
    float v = h_small[tail[e] * 32 + i] * pf[e * 4 + t];
    atomicAdd(&agg[head[e] * 128 + j], v);
}

// ------- fused2: y = relu(bn(x)) @ W^T (+ resid), 128->128, in-place-safe -
#define TILE2 32
__global__ __launch_bounds__(256) void fused2_kernel(const float* __restrict__ xin,
                                                     const float* __restrict__ scale,
                                                     const float* __restrict__ shift,
                                                     const float* __restrict__ W,
                                                     float* yout, const float* resid) {
    __shared__ __align__(16) float xn[TILE2][132];
    __shared__ __align__(16) float Wl[64][132];
    int tid = threadIdx.x;
    int n0  = blockIdx.x * TILE2;

    for (int i = tid; i < TILE2 * 128; i += 256) {
        int r = i >> 7, c = i & 127;
        float v = xin[(n0 + r) * 128 + c];
        v = v * scale[c] + shift[c];
        xn[r][c] = v > 0.f ? v : 0.f;
    }
    for (int i = tid; i < 64 * 128; i += 256) Wl[i >> 7][i & 127] = W[i];
    __syncthreads();

    int r = tid >> 3;   // 0..31
    int s = tid & 7;    // 0..7
    float acc0[8], acc1[8];
#pragma unroll
    for (int k = 0; k < 8; k++) acc0[k] = 0.f;
    for (int c = 0; c < 128; c += 4) {
        float4 xv = *(const float4*)&xn[r][c];
#pragma unroll
        for (int k = 0; k < 8; k++) {
            float4 wv = *(const float4*)&Wl[s + 8 * k][c];
            acc0[k] += xv.x * wv.x + xv.y * wv.y + xv.z * wv.z + xv.w * wv.w;
        }
    }
    __syncthreads();
    for (int i = tid; i < 64 * 128; i += 256) Wl[i >> 7][i & 127] = W[64 * 128 + i];
    __syncthreads();
#pragma unroll
    for (int k = 0; k < 8; k++) acc1[k] = 0.f;
    for (int c = 0; c < 128; c += 4) {
        float4 xv = *(const float4*)&xn[r][c];
#pragma unroll
        for (int k = 0; k < 8; k++) {
            float4 wv = *(const float4*)&Wl[s + 8 * k][c];
            acc1[k] += xv.x * wv.x + xv.y * wv.y + xv.z * wv.z + xv.w * wv.w;
        }
    }
    int n = n0 + r;
#pragma unroll
    for (int k = 0; k < 8; k++) {
        int o = s + 8 * k;
        float v0 = acc0[k], v1 = acc1[k];
        if (resid) { v0 += resid[n * 128 + o]; v1 += resid[n * 128 + 64 + o]; }
        yout[n * 128 + o]      = v0;
        yout[n * 128 + 64 + o] = v1;
    }
}

extern "C" void kernel_launch(void* const* d_in, const int* in_sizes, int n_in,
                              void* d_out, int out_size, void* d_ws, size_t ws_size,
                              hipStream_t stream) {
    const float* x    = (const float*)d_in[0];
    const float* w    = (const float*)d_in[1];
    const float* pf   = (const float*)d_in[2];
    const int*   head = (const int*)d_in[3];
    const int*   tail = (const int*)d_in[4];
    const int*   ind  = (const int*)d_in[5];
    const float* Wsc  = (const float*)d_in[6];
    const float* g1   = (const float*)d_in[7];
    const float* b1   = (const float*)d_in[8];
    const float* W1   = (const float*)d_in[9];
    const float* g2   = (const float*)d_in[10];
    const float* b2   = (const float*)d_in[11];
    const float* W2   = (const float*)d_in[12];
    const float* g3   = (const float*)d_in[13];
    const float* b3   = (const float*)d_in[14];
    const float* W3   = (const float*)d_in[15];
    float* out = (float*)d_out;

    float* ws      = (float*)d_ws;
    float* h_small = ws;                                  // N*32
    float* agg     = h_small + (size_t)N_NODES * 32;      // N*128 (reused as h2)
    float* jet     = agg + (size_t)N_NODES * 128;         // 1024*128
    float* sc1 = jet + 1024 * 128;  float* sh1 = sc1 + 64;
    float* sc2 = sh1 + 64;          float* sh2 = sc2 + 128;
    float* sc3 = sh2 + 128;         float* sh3 = sc3 + 128;

    // ---- BN1 stats ----
    hipMemsetAsync(jet, 0, 1024 * 64 * sizeof(float), stream);
    jet_kernel<64><<<(N_NODES * 64 + 255) / 256, 256, 0, stream>>>(x, w, ind, jet);
    stats_kernel<64><<<64, 256, 0, stream>>>(jet, g1, b1, sc1, sh1);

    // ---- shortcut + layer1 ----
    fused1_kernel<<<(N_NODES + TILE1 - 1) / TILE1, 256, 0, stream>>>(
        x, w, sc1, sh1, Wsc, W1, h_small, out);

    // ---- edge message passing ----
    hipMemsetAsync(agg, 0, (size_t)N_NODES * 128 * sizeof(float), stream);
    edge_kernel<<<(N_EDGES * 128) / 256, 256, 0, stream>>>(head, tail, pf, h_small, agg);

    // ---- BN2 + layer2 (in place on agg) ----
    hipMemsetAsync(jet, 0, 1024 * 128 * sizeof(float), stream);
    jet_kernel<128><<<(N_NODES * 128 + 255) / 256, 256, 0, stream>>>(agg, w, ind, jet);
    stats_kernel<128><<<128, 256, 0, stream>>>(jet, g2, b2, sc2, sh2);
    fused2_kernel<<<(N_NODES + TILE2 - 1) / TILE2, 256, 0, stream>>>(
        agg, sc2, sh2, W2, agg, nullptr);

    // ---- BN3 + layer3 + shortcut add ----
    hipMemsetAsync(jet, 0, 1024 * 128 * sizeof(float), stream);
    jet_kernel<128><<<(N_NODES * 128 + 255) / 256, 256, 0, stream>>>(agg, w, ind, jet);
    stats_kernel<128><<<128, 256, 0, stream>>>(jet, g3, b3, sc3, sh3);
    fused2_kernel<<<(N_NODES + TILE2 - 1) / TILE2, 256, 0, stream>>>(
        agg, sc3, sh3, W3, out, out);

    (void)in_sizes; (void)n_in; (void)out_size; (void)ws_size;
}

// Round 2
// 918.199 us; speedup vs baseline: 1.1735x; 1.1735x over previous
//
#include <hip/hip_runtime.h>

#define N_NODES 100000
#define N_EDGES 1600000
#define NB      1024
#define EPSF    1e-5f

// ---------------- segment-sum jet = segment_sum(x*w, ind, B) -------------
template<int C>
__global__ __launch_bounds__(256) void jet_kernel(const float* __restrict__ x,
                                                  const float* __restrict__ w,
                                                  const int* __restrict__ ind,
                                                  float* __restrict__ jet) {
    int tid = blockIdx.x * 256 + threadIdx.x;
    if (tid >= N_NODES * C) return;
    int n = tid / C;
    int c = tid % C;
    float v = x[tid] * w[n];
    atomicAdd(&jet[ind[n] * C + c], v);
}

// -------------- per-channel mean/var(ddof=1) -> scale/shift --------------
template<int C>
__global__ __launch_bounds__(256) void stats_kernel(const float* __restrict__ jet,
                                                    const float* __restrict__ g,
                                                    const float* __restrict__ b,
                                                    float* __restrict__ scale,
                                                    float* __restrict__ shift) {
    int c = blockIdx.x;
    int t = threadIdx.x;
    float s = 0.f, s2 = 0.f;
    for (int r = t; r < NB; r += 256) {
        float v = jet[r * C + c];
        s += v; s2 += v * v;
    }
    __shared__ float ls[256], ls2[256];
    ls[t] = s; ls2[t] = s2;
    __syncthreads();
    for (int ofs = 128; ofs > 0; ofs >>= 1) {
        if (t < ofs) { ls[t] += ls[t + ofs]; ls2[t] += ls2[t + ofs]; }
        __syncthreads();
    }
    if (t == 0) {
        float mean = ls[0] / (float)NB;
        float var  = (ls2[0] - (float)NB * mean * mean) / (float)(NB - 1);
        float sc   = g[c] / sqrtf(var + EPSF);
        scale[c] = sc;
        shift[c] = b[c] - mean * sc;
    }
}

// --------- fused1: shortcut GEMM + bn1+relu + @W1^T * w  -----------------
#define TILE1 16
__global__ __launch_bounds__(256) void fused1_kernel(const float* __restrict__ x,
                                                     const float* __restrict__ w,
                                                     const float* __restrict__ scale,
                                                     const float* __restrict__ shift,
                                                     const float* __restrict__ Wsc,
                                                     const float* __restrict__ W1,
                                                     float* __restrict__ h_small,
                                                     float* __restrict__ out) {
    __shared__ __align__(16) float xs[TILE1][68];
    __shared__ __align__(16) float xn[TILE1][68];
    __shared__ __align__(16) float Wl[160][68];
    int tid = threadIdx.x;
    int n0  = blockIdx.x * TILE1;

    for (int i = tid; i < 128 * 64; i += 256) Wl[i >> 6][i & 63] = Wsc[i];
    for (int i = tid; i < 32 * 64;  i += 256) Wl[128 + (i >> 6)][i & 63] = W1[i];
    for (int i = tid; i < TILE1 * 64; i += 256) {
        int r = i >> 6, c = i & 63;
        int n = n0 + r;
        float v = (n < N_NODES) ? x[n * 64 + c] : 0.f;
        xs[r][c] = v;
        float vn = v * scale[c] + shift[c];
        xn[r][c] = vn > 0.f ? vn : 0.f;
    }
    __syncthreads();

    int r = tid >> 4;
    int s = tid & 15;
    float acc[10];
#pragma unroll
    for (int k = 0; k < 10; k++) acc[k] = 0.f;

    for (int c = 0; c < 64; c += 4) {
        float4 xr  = *(const float4*)&xs[r][c];
        float4 xnr = *(const float4*)&xn[r][c];
#pragma unroll
        for (int k = 0; k < 10; k++) {
            int row = (k < 8) ? (s + 16 * k) : (128 + s + 16 * (k - 8));
            float4 wv = *(const float4*)&Wl[row][c];
            float4 xv = (k < 8) ? xr : xnr;
            acc[k] += xv.x * wv.x + xv.y * wv.y + xv.z * wv.z + xv.w * wv.w;
        }
    }
    int n = n0 + r;
    if (n < N_NODES) {
        float ww = w[n];
#pragma unroll
        for (int k = 0; k < 8; k++) out[n * 128 + s + 16 * k] = acc[k];
#pragma unroll
        for (int k = 8; k < 10; k++) h_small[n * 32 + s + 16 * (k - 8)] = acc[k] * ww;
    }
}

// ---------------- CSR build: count -> scan -> scatter --------------------
__global__ __launch_bounds__(256) void count_kernel(const int* __restrict__ head,
                                                    int* __restrict__ cnt) {
    int e = blockIdx.x * 256 + threadIdx.x;
    if (e < N_EDGES) atomicAdd(&cnt[head[e]], 1);
}

__global__ __launch_bounds__(1024) void scan_kernel(const int* __restrict__ cnt,
                                                    int* __restrict__ base) {
    __shared__ int part[1024];
    int t = threadIdx.x;
    const int CHUNK = (N_NODES + 1023) / 1024;   // 98
    int lo = t * CHUNK;
    int hi = lo + CHUNK; if (hi > N_NODES) hi = N_NODES;
    int s = 0;
    for (int i = lo; i < hi; i++) s += cnt[i];
    part[t] = s;
    __syncthreads();
    for (int ofs = 1; ofs < 1024; ofs <<= 1) {
        int v = (t >= ofs) ? part[t - ofs] : 0;
        __syncthreads();
        part[t] += v;
        __syncthreads();
    }
    int run = (t > 0) ? part[t - 1] : 0;
    for (int i = lo; i < hi; i++) { base[i] = run; run += cnt[i]; }
}

__global__ __launch_bounds__(256) void scatter_kernel(const int* __restrict__ head,
                                                      const int* __restrict__ base,
                                                      int* __restrict__ cursor,
                                                      int* __restrict__ eid) {
    int e = blockIdx.x * 256 + threadIdx.x;
    if (e < N_EDGES) {
        int h = head[e];
        int slot = base[h] + atomicAdd(&cursor[h], 1);
        eid[slot] = e;
    }
}

// ---------- gather: agg[n,j] = sum_{e in CSR[n]} h_small[tail_e]*pf_e -----
// 256 threads = 2 nodes x 128 channels; fused jet2 atomic epilogue
__global__ __launch_bounds__(256) void gather_kernel(const int* __restrict__ base,
                                                     const int* __restrict__ cnt,
                                                     const int* __restrict__ eid,
                                                     const int* __restrict__ tail,
                                                     const float* __restrict__ pf,
                                                     const float* __restrict__ h_small,
                                                     const float* __restrict__ w,
                                                     const int* __restrict__ ind,
                                                     float* __restrict__ agg,
                                                     float* __restrict__ jet2) {
    int tid = threadIdx.x;
    int n = blockIdx.x * 2 + (tid >> 7);
    if (n >= N_NODES) return;
    int j = tid & 127;
    int i = j >> 2, t = j & 3;
    int s0 = base[n], c = cnt[n];
    float acc = 0.f;
    int k = 0;
    for (; k + 1 < c; k += 2) {               // 2-deep pipeline: independent loads
        int ea = eid[s0 + k], eb = eid[s0 + k + 1];
        int ta = tail[ea],    tb = tail[eb];
        float pa = pf[ea * 4 + t], pb = pf[eb * 4 + t];
        float ha = h_small[ta * 32 + i], hb = h_small[tb * 32 + i];
        acc += ha * pa;
        acc += hb * pb;
    }
    if (k < c) {
        int ea = eid[s0 + k];
        acc += h_small[tail[ea] * 32 + i] * pf[ea * 4 + t];
    }
    agg[n * 128 + j] = acc;
    atomicAdd(&jet2[ind[n] * 128 + j], acc * w[n]);
}

// ------- fused2: y = relu(bn(x)) @ W^T (+resid) (+jet atomic epilogue) ----
#define TILE2 32
__global__ __launch_bounds__(256) void fused2_kernel(const float* __restrict__ xin,
                                                     const float* __restrict__ scale,
                                                     const float* __restrict__ shift,
                                                     const float* __restrict__ W,
                                                     float* yout, const float* resid,
                                                     const float* __restrict__ w,
                                                     const int* __restrict__ ind,
                                                     float* jet_next) {
    __shared__ __align__(16) float xn[TILE2][132];
    __shared__ __align__(16) float Wl[64][132];
    int tid = threadIdx.x;
    int n0  = blockIdx.x * TILE2;

    for (int i = tid; i < TILE2 * 128; i += 256) {
        int r = i >> 7, c = i & 127;
        float v = xin[(n0 + r) * 128 + c];
        v = v * scale[c] + shift[c];
        xn[r][c] = v > 0.f ? v : 0.f;
    }
    for (int i = tid; i < 64 * 128; i += 256) Wl[i >> 7][i & 127] = W[i];
    __syncthreads();

    int r = tid >> 3;
    int s = tid & 7;
    float acc0[8], acc1[8];
#pragma unroll
    for (int k = 0; k < 8; k++) acc0[k] = 0.f;
    for (int c = 0; c < 128; c += 4) {
        float4 xv = *(const float4*)&xn[r][c];
#pragma unroll
        for (int k = 0; k < 8; k++) {
            float4 wv = *(const float4*)&Wl[s + 8 * k][c];
            acc0[k] += xv.x * wv.x + xv.y * wv.y + xv.z * wv.z + xv.w * wv.w;
        }
    }
    __syncthreads();
    for (int i = tid; i < 64 * 128; i += 256) Wl[i >> 7][i & 127] = W[64 * 128 + i];
    __syncthreads();
#pragma unroll
    for (int k = 0; k < 8; k++) acc1[k] = 0.f;
    for (int c = 0; c < 128; c += 4) {
        float4 xv = *(const float4*)&xn[r][c];
#pragma unroll
        for (int k = 0; k < 8; k++) {
            float4 wv = *(const float4*)&Wl[s + 8 * k][c];
            acc1[k] += xv.x * wv.x + xv.y * wv.y + xv.z * wv.z + xv.w * wv.w;
        }
    }
    int n = n0 + r;
    float ww = (jet_next != nullptr) ? w[n] : 0.f;
    int bslot = (jet_next != nullptr) ? ind[n] : 0;
#pragma unroll
    for (int k = 0; k < 8; k++) {
        int o = s + 8 * k;
        float v0 = acc0[k], v1 = acc1[k];
        if (resid) { v0 += resid[n * 128 + o]; v1 += resid[n * 128 + 64 + o]; }
        yout[n * 128 + o]      = v0;
        yout[n * 128 + 64 + o] = v1;
        if (jet_next) {
            atomicAdd(&jet_next[bslot * 128 + o],      v0 * ww);
            atomicAdd(&jet_next[bslot * 128 + 64 + o], v1 * ww);
        }
    }
}

// -------- legacy atomic edge scatter (fallback if ws too small) ----------
__global__ __launch_bounds__(256) void edge_kernel(const int* __restrict__ head,
                                                   const int* __restrict__ tail,
                                                   const float* __restrict__ pf,
                                                   const float* __restrict__ h_small,
                                                   float* __restrict__ agg) {
    long long tid = (long long)blockIdx.x * 256 + threadIdx.x;
    if (tid >= (long long)N_EDGES * 128) return;
    int e = (int)(tid >> 7);
    int j = (int)(tid & 127);
    int i = j >> 2, t = j & 3;
    float v = h_small[tail[e] * 32 + i] * pf[e * 4 + t];
    atomicAdd(&agg[head[e] * 128 + j], v);
}

extern "C" void kernel_launch(void* const* d_in, const int* in_sizes, int n_in,
                              void* d_out, int out_size, void* d_ws, size_t ws_size,
                              hipStream_t stream) {
    const float* x    = (const float*)d_in[0];
    const float* w    = (const float*)d_in[1];
    const float* pf   = (const float*)d_in[2];
    const int*   head = (const int*)d_in[3];
    const int*   tail = (const int*)d_in[4];
    const int*   ind  = (const int*)d_in[5];
    const float* Wsc  = (const float*)d_in[6];
    const float* g1   = (const float*)d_in[7];
    const float* b1   = (const float*)d_in[8];
    const float* W1   = (const float*)d_in[9];
    const float* g2   = (const float*)d_in[10];
    const float* b2   = (const float*)d_in[11];
    const float* W2   = (const float*)d_in[12];
    const float* g3   = (const float*)d_in[13];
    const float* b3   = (const float*)d_in[14];
    const float* W3   = (const float*)d_in[15];
    float* out = (float*)d_out;

    float* ws      = (float*)d_ws;
    float* h_small = ws;                                    // N*32
    float* agg     = h_small + (size_t)N_NODES * 32;        // N*128
    float* jet1    = agg + (size_t)N_NODES * 128;           // 1024*64
    float* jet2    = jet1 + 1024 * 64;                      // 1024*128
    float* jet3    = jet2 + 1024 * 128;                     // 1024*128
    float* sc1 = jet3 + 1024 * 128; float* sh1 = sc1 + 64;
    float* sc2 = sh1 + 64;          float* sh2 = sc2 + 128;
    float* sc3 = sh2 + 128;         float* sh3 = sc3 + 128;
    int*   cnt    = (int*)(sh3 + 128);                      // N
    int*   basep  = cnt + N_NODES;                          // N
    int*   cursor = basep + N_NODES;                        // N
    int*   eid    = cursor + N_NODES;                       // E
    size_t need_bytes = (size_t)((char*)(eid + N_EDGES) - (char*)d_ws);
    bool use_csr = ws_size >= need_bytes;

    // ---- zero the small accumulators ----
    hipMemsetAsync(jet1, 0, 1024 * 64 * sizeof(float), stream);
    hipMemsetAsync(jet2, 0, 1024 * 128 * sizeof(float), stream);
    hipMemsetAsync(jet3, 0, 1024 * 128 * sizeof(float), stream);

    // ---- BN1 stats ----
    jet_kernel<64><<<(N_NODES * 64 + 255) / 256, 256, 0, stream>>>(x, w, ind, jet1);
    stats_kernel<64><<<64, 256, 0, stream>>>(jet1, g1, b1, sc1, sh1);

    // ---- shortcut + layer1 ----
    fused1_kernel<<<(N_NODES + TILE1 - 1) / TILE1, 256, 0, stream>>>(
        x, w, sc1, sh1, Wsc, W1, h_small, out);

    // ---- edge message passing ----
    if (use_csr) {
        hipMemsetAsync(cnt, 0, N_NODES * sizeof(int), stream);
        hipMemsetAsync(cursor, 0, N_NODES * sizeof(int), stream);
        count_kernel<<<(N_EDGES + 255) / 256, 256, 0, stream>>>(head, cnt);
        scan_kernel<<<1, 1024, 0, stream>>>(cnt, basep);
        scatter_kernel<<<(N_EDGES + 255) / 256, 256, 0, stream>>>(head, basep, cursor, eid);
        gather_kernel<<<(N_NODES + 1) / 2, 256, 0, stream>>>(
            basep, cnt, eid, tail, pf, h_small, w, ind, agg, jet2);
    } else {
        hipMemsetAsync(agg, 0, (size_t)N_NODES * 128 * sizeof(float), stream);
        edge_kernel<<<(int)(((long long)N_EDGES * 128) / 256), 256, 0, stream>>>(
            head, tail, pf, h_small, agg);
        jet_kernel<128><<<(N_NODES * 128 + 255) / 256, 256, 0, stream>>>(agg, w, ind, jet2);
    }

    // ---- BN2 + layer2 (in place on agg, jet3 fused) ----
    stats_kernel<128><<<128, 256, 0, stream>>>(jet2, g2, b2, sc2, sh2);
    fused2_kernel<<<(N_NODES + TILE2 - 1) / TILE2, 256, 0, stream>>>(
        agg, sc2, sh2, W2, agg, nullptr, w, ind, jet3);

    // ---- BN3 + layer3 + shortcut add ----
    stats_kernel<128><<<128, 256, 0, stream>>>(jet3, g3, b3, sc3, sh3);
    fused2_kernel<<<(N_NODES + TILE2 - 1) / TILE2, 256, 0, stream>>>(
        agg, sc3, sh3, W3, out, out, nullptr, nullptr, nullptr);

    (void)in_sizes; (void)n_in; (void)out_size;
}

// Round 3
// 643.843 us; speedup vs baseline: 1.6735x; 1.4261x over previous
//
#include <hip/hip_runtime.h>

#define N_NODES 100000
#define N_EDGES 1600000
#define NB      1024
#define EPSF    1e-5f

#define SCHUNK 128
#define SNBLK ((N_NODES + SCHUNK - 1) / SCHUNK)   // 782

// -------------- per-channel mean/var(ddof=1) -> scale/shift --------------
template<int C>
__global__ __launch_bounds__(256) void stats_kernel(const float* __restrict__ jet,
                                                    const float* __restrict__ g,
                                                    const float* __restrict__ b,
                                                    float* __restrict__ scale,
                                                    float* __restrict__ shift) {
    int c = blockIdx.x;
    int t = threadIdx.x;
    float s = 0.f, s2 = 0.f;
    for (int r = t; r < NB; r += 256) {
        float v = jet[r * C + c];
        s += v; s2 += v * v;
    }
    __shared__ float ls[256], ls2[256];
    ls[t] = s; ls2[t] = s2;
    __syncthreads();
    for (int ofs = 128; ofs > 0; ofs >>= 1) {
        if (t < ofs) { ls[t] += ls[t + ofs]; ls2[t] += ls2[t + ofs]; }
        __syncthreads();
    }
    if (t == 0) {
        float mean = ls[0] / (float)NB;
        float var  = (ls2[0] - (float)NB * mean * mean) / (float)(NB - 1);
        float sc   = g[c] / sqrtf(var + EPSF);
        scale[c] = sc;
        shift[c] = b[c] - mean * sc;
    }
}

// ---------------- generic count kernels ----------------------------------
__global__ __launch_bounds__(256) void count_head_kernel(const int* __restrict__ head,
                                                         int* __restrict__ cnt) {
    int e = blockIdx.x * 256 + threadIdx.x;
    if (e < N_EDGES) atomicAdd(&cnt[head[e]], 1);
}
__global__ __launch_bounds__(256) void countI_kernel(const int* __restrict__ ind,
                                                     int* __restrict__ cntI) {
    int n = blockIdx.x * 256 + threadIdx.x;
    if (n < N_NODES) atomicAdd(&cntI[ind[n]], 1);
}

// ---------------- 3-stage parallel exclusive scan over N_NODES -----------
__global__ __launch_bounds__(SCHUNK) void scanA_kernel(const int* __restrict__ cnt,
                                                       int* __restrict__ part) {
    __shared__ int ls[SCHUNK];
    int t = threadIdx.x;
    int i = blockIdx.x * SCHUNK + t;
    ls[t] = (i < N_NODES) ? cnt[i] : 0;
    __syncthreads();
    for (int ofs = SCHUNK / 2; ofs > 0; ofs >>= 1) {
        if (t < ofs) ls[t] += ls[t + ofs];
        __syncthreads();
    }
    if (t == 0) part[blockIdx.x] = ls[0];
}

// single-block scan (n <= 1024); writes EXCLUSIVE prefix to out (and out2)
__global__ __launch_bounds__(1024) void scanB_kernel(const int* __restrict__ in,
                                                     int* __restrict__ out,
                                                     int* __restrict__ out2, int n) {
    __shared__ int ls[1024];
    int t = threadIdx.x;
    int v = (t < n) ? in[t] : 0;
    ls[t] = v;
    __syncthreads();
    for (int ofs = 1; ofs < 1024; ofs <<= 1) {
        int u = (t >= ofs) ? ls[t - ofs] : 0;
        __syncthreads();
        ls[t] += u;
        __syncthreads();
    }
    if (t < n) {
        int e = ls[t] - v;
        out[t] = e;
        if (out2) out2[t] = e;
    }
}

__global__ __launch_bounds__(SCHUNK) void scanC_kernel(const int* __restrict__ cnt,
                                                       const int* __restrict__ poff,
                                                       int* __restrict__ base,
                                                       int* __restrict__ cursor) {
    __shared__ int ls[SCHUNK];
    int t = threadIdx.x;
    int i = blockIdx.x * SCHUNK + t;
    int v = (i < N_NODES) ? cnt[i] : 0;
    ls[t] = v;
    __syncthreads();
    for (int ofs = 1; ofs < SCHUNK; ofs <<= 1) {
        int u = (t >= ofs) ? ls[t - ofs] : 0;
        __syncthreads();
        ls[t] += u;
        __syncthreads();
    }
    if (i < N_NODES) {
        int bse = poff[blockIdx.x] + ls[t] - v;
        base[i] = bse;
        cursor[i] = bse;
    }
}

// ---------------- scatter (edge -> CSR slot, pre-gathered) ---------------
template<int PRE>
__global__ __launch_bounds__(256) void escatter_kernel(const int* __restrict__ head,
                                                       const int* __restrict__ tail,
                                                       const float* __restrict__ pf,
                                                       int* __restrict__ cursor,
                                                       int* __restrict__ tail_s,
                                                       float* __restrict__ pf_s,
                                                       int* __restrict__ eid) {
    int e = blockIdx.x * 256 + threadIdx.x;
    if (e >= N_EDGES) return;
    int slot = atomicAdd(&cursor[head[e]], 1);
    if (PRE) {
        tail_s[slot] = tail[e];
        ((float4*)pf_s)[slot] = ((const float4*)pf)[e];
    } else {
        eid[slot] = e;
    }
}

__global__ __launch_bounds__(256) void scatterI_kernel(const int* __restrict__ ind,
                                                       int* __restrict__ cursorI,
                                                       int* __restrict__ order) {
    int n = blockIdx.x * 256 + threadIdx.x;
    if (n < N_NODES) {
        int pos = atomicAdd(&cursorI[ind[n]], 1);
        order[pos] = n;
    }
}

// ---------- bucket jet: jet[b,c] = sum_{n in bucket b} x[n,c]*w[n] -------
template<int C>
__global__ __launch_bounds__(256) void bucket_jet_kernel(const float* __restrict__ xx,
                                                         const float* __restrict__ w,
                                                         const int* __restrict__ order,
                                                         const int* __restrict__ baseI,
                                                         const int* __restrict__ cntI,
                                                         float* __restrict__ jet) {
    constexpr int G = 256 / C;
    __shared__ float red[256];
    int b = blockIdx.x;
    int g = threadIdx.x / C;
    int c = threadIdx.x % C;
    int s0 = baseI[b], m = cntI[b];
    float s = 0.f;
    for (int k = g; k < m; k += G) {
        int n = order[s0 + k];
        s += xx[n * C + c] * w[n];
    }
    red[threadIdx.x] = s;
    __syncthreads();
    for (int half = G / 2; half > 0; half >>= 1) {
        if (g < half) red[g * C + c] += red[(g + half) * C + c];
        __syncthreads();
    }
    if (g == 0) jet[b * C + c] = red[c];
}

// --------- fused1: shortcut GEMM + bn1+relu + @W1^T * w  -----------------
// 32-row tile; 256 threads = 16 row-threads (2 rows each) x 16 col-groups
#define TILE1 32
__global__ __launch_bounds__(256) void fused1_kernel(const float* __restrict__ x,
                                                     const float* __restrict__ w,
                                                     const float* __restrict__ scale,
                                                     const float* __restrict__ shift,
                                                     const float* __restrict__ Wsc,
                                                     const float* __restrict__ W1,
                                                     float* __restrict__ h_small,
                                                     float* __restrict__ out) {
    __shared__ __align__(16) float xs[TILE1][68];
    __shared__ __align__(16) float xn[TILE1][68];
    __shared__ __align__(16) float Wl[160][68];
    int tid = threadIdx.x;
    int n0  = blockIdx.x * TILE1;

    for (int i = tid; i < 128 * 64; i += 256) Wl[i >> 6][i & 63] = Wsc[i];
    for (int i = tid; i < 32 * 64;  i += 256) Wl[128 + (i >> 6)][i & 63] = W1[i];
    for (int i = tid; i < TILE1 * 64; i += 256) {
        int r = i >> 6, c = i & 63;
        int n = n0 + r;
        float v = (n < N_NODES) ? x[n * 64 + c] : 0.f;
        xs[r][c] = v;
        float vn = v * scale[c] + shift[c];
        xn[r][c] = vn > 0.f ? vn : 0.f;
    }
    __syncthreads();

    int r0 = tid >> 4;     // 0..15 -> rows r0, r0+16
    int s  = tid & 15;     // 0..15
    float acc[2][10];
#pragma unroll
    for (int q = 0; q < 2; q++)
#pragma unroll
        for (int k = 0; k < 10; k++) acc[q][k] = 0.f;

    for (int c = 0; c < 64; c += 4) {
        float4 xr0 = *(const float4*)&xs[r0][c];
        float4 xr1 = *(const float4*)&xs[r0 + 16][c];
        float4 xn0 = *(const float4*)&xn[r0][c];
        float4 xn1 = *(const float4*)&xn[r0 + 16][c];
#pragma unroll
        for (int k = 0; k < 10; k++) {
            int row = (k < 8) ? (s + 16 * k) : (128 + s + 16 * (k - 8));
            float4 wv = *(const float4*)&Wl[row][c];
            float4 a0 = (k < 8) ? xr0 : xn0;
            float4 a1 = (k < 8) ? xr1 : xn1;
            acc[0][k] += a0.x * wv.x + a0.y * wv.y + a0.z * wv.z + a0.w * wv.w;
            acc[1][k] += a1.x * wv.x + a1.y * wv.y + a1.z * wv.z + a1.w * wv.w;
        }
    }
#pragma unroll
    for (int q = 0; q < 2; q++) {
        int n = n0 + r0 + 16 * q;
        if (n < N_NODES) {
            float ww = w[n];
#pragma unroll
            for (int k = 0; k < 8; k++) out[n * 128 + s + 16 * k] = acc[q][k];
            h_small[n * 32 + s]      = acc[q][8] * ww;
            h_small[n * 32 + s + 16] = acc[q][9] * ww;
        }
    }
}

// ---------- gather: one wave per node, lane = channel pair ---------------
template<int PRE>
__global__ __launch_bounds__(256) void gather2_kernel(const int* __restrict__ base,
                                                      const int* __restrict__ cnt,
                                                      const int* __restrict__ tail_s,
                                                      const float* __restrict__ pf_s,
                                                      const int* __restrict__ eid,
                                                      const int* __restrict__ tail,
                                                      const float* __restrict__ pf,
                                                      const float* __restrict__ h_small,
                                                      float* __restrict__ agg) {
    int n = blockIdx.x * 4 + (threadIdx.x >> 6);
    if (n >= N_NODES) return;
    int lane = threadIdx.x & 63;
    int i = lane >> 1;
    int th = (lane & 1) * 2;
    int s0 = base[n], c = cnt[n];
    float a0 = 0.f, a1 = 0.f;
    int k = 0;
    for (; k + 4 <= c; k += 4) {
        int t0, t1, t2, t3;
        float2 p0, p1, p2, p3;
        if (PRE) {
            t0 = tail_s[s0 + k];     t1 = tail_s[s0 + k + 1];
            t2 = tail_s[s0 + k + 2]; t3 = tail_s[s0 + k + 3];
            p0 = *(const float2*)&pf_s[(s0 + k) * 4 + th];
            p1 = *(const float2*)&pf_s[(s0 + k + 1) * 4 + th];
            p2 = *(const float2*)&pf_s[(s0 + k + 2) * 4 + th];
            p3 = *(const float2*)&pf_s[(s0 + k + 3) * 4 + th];
        } else {
            int e0 = eid[s0 + k],     e1 = eid[s0 + k + 1];
            int e2 = eid[s0 + k + 2], e3 = eid[s0 + k + 3];
            t0 = tail[e0]; t1 = tail[e1]; t2 = tail[e2]; t3 = tail[e3];
            p0 = *(const float2*)&pf[e0 * 4 + th];
            p1 = *(const float2*)&pf[e1 * 4 + th];
            p2 = *(const float2*)&pf[e2 * 4 + th];
            p3 = *(const float2*)&pf[e3 * 4 + th];
        }
        float h0 = h_small[t0 * 32 + i];
        float h1 = h_small[t1 * 32 + i];
        float h2 = h_small[t2 * 32 + i];
        float h3 = h_small[t3 * 32 + i];
        a0 += h0 * p0.x; a1 += h0 * p0.y;
        a0 += h1 * p1.x; a1 += h1 * p1.y;
        a0 += h2 * p2.x; a1 += h2 * p2.y;
        a0 += h3 * p3.x; a1 += h3 * p3.y;
    }
    for (; k < c; k++) {
        int t0; float2 p0;
        if (PRE) {
            t0 = tail_s[s0 + k];
            p0 = *(const float2*)&pf_s[(s0 + k) * 4 + th];
        } else {
            int e0 = eid[s0 + k];
            t0 = tail[e0];
            p0 = *(const float2*)&pf[e0 * 4 + th];
        }
        float h0 = h_small[t0 * 32 + i];
        a0 += h0 * p0.x; a1 += h0 * p0.y;
    }
    *(float2*)&agg[n * 128 + lane * 2] = make_float2(a0, a1);
}

// -------- legacy atomic edge scatter (ultimate fallback) -----------------
__global__ __launch_bounds__(256) void edge_kernel(const int* __restrict__ head,
                                                   const int* __restrict__ tail,
                                                   const float* __restrict__ pf,
                                                   const float* __restrict__ h_small,
                                                   float* __restrict__ agg) {
    long long tid = (long long)blockIdx.x * 256 + threadIdx.x;
    if (tid >= (long long)N_EDGES * 128) return;
    int e = (int)(tid >> 7);
    int j = (int)(tid & 127);
    int i = j >> 2, t = j & 3;
    float v = h_small[tail[e] * 32 + i] * pf[e * 4 + t];
    atomicAdd(&agg[head[e] * 128 + j], v);
}

// ------- fused2: y = relu(bn(x)) @ W^T (+resid), 2 rows/thread -----------
#define TILE2 32
__global__ __launch_bounds__(256) void fused2_kernel(const float* __restrict__ xin,
                                                     const float* __restrict__ scale,
                                                     const float* __restrict__ shift,
                                                     const float* __restrict__ W,
                                                     float* __restrict__ yout,
                                                     const float* __restrict__ resid) {
    __shared__ __align__(16) float xn[TILE2][132];
    __shared__ __align__(16) float Wl[64][132];
    int tid = threadIdx.x;
    int n0  = blockIdx.x * TILE2;

    for (int i = tid; i < TILE2 * 128; i += 256) {
        int r = i >> 7, c = i & 127;
        float v = xin[(n0 + r) * 128 + c];
        v = v * scale[c] + shift[c];
        xn[r][c] = v > 0.f ? v : 0.f;
    }
    for (int i = tid; i < 64 * 128; i += 256) Wl[i >> 7][i & 127] = W[i];
    __syncthreads();

    int r0 = tid >> 4;   // rows r0, r0+16
    int s  = tid & 15;   // 16 col-groups x 4 outputs per phase
    float acc0[2][4], acc1[2][4];
#pragma unroll
    for (int q = 0; q < 2; q++)
#pragma unroll
        for (int k = 0; k < 4; k++) acc0[q][k] = 0.f;

    for (int c = 0; c < 128; c += 4) {
        float4 x0 = *(const float4*)&xn[r0][c];
        float4 x1 = *(const float4*)&xn[r0 + 16][c];
#pragma unroll
        for (int k = 0; k < 4; k++) {
            float4 wv = *(const float4*)&Wl[s + 16 * k][c];
            acc0[0][k] += x0.x * wv.x + x0.y * wv.y + x0.z * wv.z + x0.w * wv.w;
            acc0[1][k] += x1.x * wv.x + x1.y * wv.y + x1.z * wv.z + x1.w * wv.w;
        }
    }
    __syncthreads();
    for (int i = tid; i < 64 * 128; i += 256) Wl[i >> 7][i & 127] = W[64 * 128 + i];
    __syncthreads();
#pragma unroll
    for (int q = 0; q < 2; q++)
#pragma unroll
        for (int k = 0; k < 4; k++) acc1[q][k] = 0.f;

    for (int c = 0; c < 128; c += 4) {
        float4 x0 = *(const float4*)&xn[r0][c];
        float4 x1 = *(const float4*)&xn[r0 + 16][c];
#pragma unroll
        for (int k = 0; k < 4; k++) {
            float4 wv = *(const float4*)&Wl[s + 16 * k][c];
            acc1[0][k] += x0.x * wv.x + x0.y * wv.y + x0.z * wv.z + x0.w * wv.w;
            acc1[1][k] += x1.x * wv.x + x1.y * wv.y + x1.z * wv.z + x1.w * wv.w;
        }
    }
#pragma unroll
    for (int q = 0; q < 2; q++) {
        int n = n0 + r0 + 16 * q;
#pragma unroll
        for (int k = 0; k < 4; k++) {
            int o0 = s + 16 * k;
            int o1 = 64 + s + 16 * k;
            float v0 = acc0[q][k], v1 = acc1[q][k];
            if (resid) { v0 += resid[n * 128 + o0]; v1 += resid[n * 128 + o1]; }
            yout[n * 128 + o0] = v0;
            yout[n * 128 + o1] = v1;
        }
    }
}

extern "C" void kernel_launch(void* const* d_in, const int* in_sizes, int n_in,
                              void* d_out, int out_size, void* d_ws, size_t ws_size,
                              hipStream_t stream) {
    const float* x    = (const float*)d_in[0];
    const float* w    = (const float*)d_in[1];
    const float* pf   = (const float*)d_in[2];
    const int*   head = (const int*)d_in[3];
    const int*   tail = (const int*)d_in[4];
    const int*   ind  = (const int*)d_in[5];
    const float* Wsc  = (const float*)d_in[6];
    const float* g1   = (const float*)d_in[7];
    const float* b1   = (const float*)d_in[8];
    const float* W1   = (const float*)d_in[9];
    const float* g2   = (const float*)d_in[10];
    const float* b2   = (const float*)d_in[11];
    const float* W2   = (const float*)d_in[12];
    const float* g3   = (const float*)d_in[13];
    const float* b3   = (const float*)d_in[14];
    const float* W3   = (const float*)d_in[15];
    float* out = (float*)d_out;

    float* fp = (float*)d_ws;
    float* h_small = fp;                               fp += (size_t)N_NODES * 32;
    float* agg     = fp;                               fp += (size_t)N_NODES * 128;
    float* jet1    = fp;                               fp += 1024 * 64;
    float* jet2    = fp;                               fp += 1024 * 128;
    float* jet3    = fp;                               fp += 1024 * 128;
    float* sc1 = fp; fp += 64;  float* sh1 = fp; fp += 64;
    float* sc2 = fp; fp += 128; float* sh2 = fp; fp += 128;
    float* sc3 = fp; fp += 128; float* sh3 = fp; fp += 128;
    int* ip = (int*)fp;
    int* cnt_e    = ip; ip += N_NODES;
    int* base_e   = ip; ip += N_NODES;
    int* cursor_e = ip; ip += N_NODES;
    int* part     = ip; ip += 1024;
    int* cntI     = ip; ip += 1024;
    int* baseI    = ip; ip += 1024;
    int* cursorI  = ip; ip += 1024;
    int* order    = ip; ip += N_NODES;
    // tier-dependent region
    int*   tail_s = ip;
    float* pf_s   = (float*)(tail_s + N_EDGES);
    int*   eid    = ip;                                // tier2 alias
    size_t need_base = (size_t)((char*)ip - (char*)d_ws);
    size_t need_t1 = need_base + (size_t)N_EDGES * 4 + (size_t)N_EDGES * 16;
    size_t need_t2 = need_base + (size_t)N_EDGES * 4;
    int tier = (ws_size >= need_t1) ? 1 : (ws_size >= need_t2) ? 2 : 3;

    // ---- indicator-CSR (for atomic-free jets) ----
    hipMemsetAsync(cntI, 0, 1024 * sizeof(int), stream);
    countI_kernel<<<(N_NODES + 255) / 256, 256, 0, stream>>>(ind, cntI);
    scanB_kernel<<<1, 1024, 0, stream>>>(cntI, baseI, cursorI, 1024);
    scatterI_kernel<<<(N_NODES + 255) / 256, 256, 0, stream>>>(ind, cursorI, order);

    // ---- BN1 stats (bucket reduction, no atomics) ----
    bucket_jet_kernel<64><<<1024, 256, 0, stream>>>(x, w, order, baseI, cntI, jet1);
    stats_kernel<64><<<64, 256, 0, stream>>>(jet1, g1, b1, sc1, sh1);

    // ---- shortcut + layer1 ----
    fused1_kernel<<<(N_NODES + TILE1 - 1) / TILE1, 256, 0, stream>>>(
        x, w, sc1, sh1, Wsc, W1, h_small, out);

    // ---- edge message passing ----
    if (tier <= 2) {
        hipMemsetAsync(cnt_e, 0, N_NODES * sizeof(int), stream);
        count_head_kernel<<<(N_EDGES + 255) / 256, 256, 0, stream>>>(head, cnt_e);
        scanA_kernel<<<SNBLK, SCHUNK, 0, stream>>>(cnt_e, part);
        scanB_kernel<<<1, 1024, 0, stream>>>(part, part, nullptr, SNBLK);
        scanC_kernel<<<SNBLK, SCHUNK, 0, stream>>>(cnt_e, part, base_e, cursor_e);
        if (tier == 1) {
            escatter_kernel<1><<<(N_EDGES + 255) / 256, 256, 0, stream>>>(
                head, tail, pf, cursor_e, tail_s, pf_s, nullptr);
            gather2_kernel<1><<<(N_NODES + 3) / 4, 256, 0, stream>>>(
                base_e, cnt_e, tail_s, pf_s, nullptr, tail, pf, h_small, agg);
        } else {
            escatter_kernel<0><<<(N_EDGES + 255) / 256, 256, 0, stream>>>(
                head, tail, pf, cursor_e, nullptr, nullptr, eid);
            gather2_kernel<0><<<(N_NODES + 3) / 4, 256, 0, stream>>>(
                base_e, cnt_e, nullptr, nullptr, eid, tail, pf, h_small, agg);
        }
    } else {
        hipMemsetAsync(agg, 0, (size_t)N_NODES * 128 * sizeof(float), stream);
        edge_kernel<<<(int)(((long long)N_EDGES * 128) / 256), 256, 0, stream>>>(
            head, tail, pf, h_small, agg);
    }

    // ---- BN2 + layer2 (in place on agg) ----
    bucket_jet_kernel<128><<<1024, 256, 0, stream>>>(agg, w, order, baseI, cntI, jet2);
    stats_kernel<128><<<128, 256, 0, stream>>>(jet2, g2, b2, sc2, sh2);
    fused2_kernel<<<(N_NODES + TILE2 - 1) / TILE2, 256, 0, stream>>>(
        agg, sc2, sh2, W2, agg, nullptr);

    // ---- BN3 + layer3 + shortcut add ----
    bucket_jet_kernel<128><<<1024, 256, 0, stream>>>(agg, w, order, baseI, cntI, jet3);
    stats_kernel<128><<<128, 256, 0, stream>>>(jet3, g3, b3, sc3, sh3);
    fused2_kernel<<<(N_NODES + TILE2 - 1) / TILE2, 256, 0, stream>>>(
        agg, sc3, sh3, W3, out, out);

    (void)in_sizes; (void)n_in; (void)out_size;
}